// Round 1
// baseline (38926.932 us; speedup 1.0000x reference)
//
#include <hip/hip_runtime.h>

typedef unsigned long long u64;
typedef unsigned int u32;

// ---------------- problem constants ----------------
#define Bz 32
#define Sz 128
#define Ez 256
#define Hz 256
#define Vz 16000
#define Tz 128

// ---------------- workspace layout (bytes) ----------------
// ws[0..1024):    encoder BarSlot[128]
// ws[1024..2048): decoder bar_b slots, one 128B line per batch-group (8 used)
// ws[2048..3072): grid barrier sub-counters, one 128B line per XCD residue
// ws[3072]:       grid barrier master counter ; ws[3200]: grid barrier gen
#define OFF_PART 8192u       // u64 partial-argmax area (we use 32*256 u64 = 64KB)
#define OFF_HS   524288u     // float[196608] = 768KB
#define OUT_XS   0u          // float[128*32*256] = 4MB  (scratch in out buffer)
#define OUT_XS1  (4u<<20)    // float[128*32*512] = 8MB

#define HS_H0A 98304
#define HS_H0B 114688
#define HS_C0  131072
#define HS_H1A 147456
#define HS_H1B 163840
#define HS_C1  180224
#define HS_N   196608

__device__ inline float sigf(float x){ return 1.0f/(1.0f+expf(-x)); }
__device__ inline u32 f2ord(float f){ u32 u=__float_as_uint(f); return (u & 0x80000000u) ? ~u : (u | 0x80000000u); }

#define ACC4(w, xp) { acc=fmaf((w).x,(xp)[0],acc); acc=fmaf((w).y,(xp)[1],acc); \
                      acc=fmaf((w).z,(xp)[2],acc); acc=fmaf((w).w,(xp)[3],acc); }

// 4-batch accumulate: xh batches are 1024 floats apart
#define ACC4X(w, p) { \
  acc0=fmaf((w).x,(p)[0],acc0);    acc0=fmaf((w).y,(p)[1],acc0);    acc0=fmaf((w).z,(p)[2],acc0);    acc0=fmaf((w).w,(p)[3],acc0); \
  acc1=fmaf((w).x,(p)[1024],acc1); acc1=fmaf((w).y,(p)[1025],acc1); acc1=fmaf((w).z,(p)[1026],acc1); acc1=fmaf((w).w,(p)[1027],acc1); \
  acc2=fmaf((w).x,(p)[2048],acc2); acc2=fmaf((w).y,(p)[2049],acc2); acc2=fmaf((w).z,(p)[2050],acc2); acc2=fmaf((w).w,(p)[2051],acc2); \
  acc3=fmaf((w).x,(p)[3072],acc3); acc3=fmaf((w).y,(p)[3073],acc3); acc3=fmaf((w).z,(p)[3074],acc3); acc3=fmaf((w).w,(p)[3075],acc3); }

struct BarSlot { u32 cnt; u32 gen; };

// Generation barrier (small participant counts: encoder 4-way, decoder bar_b 16-way).
__device__ inline void block_bar(BarSlot* s, u32 nblk, u32 target){
  __syncthreads();
  if (threadIdx.x == 0){
    u32 old = __hip_atomic_fetch_add(&s->cnt, 1u, __ATOMIC_ACQ_REL, __HIP_MEMORY_SCOPE_AGENT);
    if (old == nblk-1u){
      __hip_atomic_store(&s->cnt, 0u, __ATOMIC_RELAXED, __HIP_MEMORY_SCOPE_AGENT);
      __hip_atomic_fetch_add(&s->gen, 1u, __ATOMIC_RELEASE, __HIP_MEMORY_SCOPE_AGENT);
    } else {
      while (__hip_atomic_load(&s->gen, __ATOMIC_ACQUIRE, __HIP_MEMORY_SCOPE_AGENT) < target){
        __builtin_amdgcn_s_sleep(2);
      }
    }
  }
  __syncthreads();
}

// Two-level 256-block grid barrier: 8 sub-lines (32 arrivals each, parallel across lines),
// 8 master arrivals, gen word on its own cacheline so polls don't fight arrival RMWs.
__device__ inline void grid_bar(char* ws, u32 target){
  __syncthreads();
  if (threadIdx.x == 0){
    u32* sub  = (u32*)(ws + 2048 + (size_t)(blockIdx.x & 7)*128);
    u32* mcnt = (u32*)(ws + 3072);
    u32* gen  = (u32*)(ws + 3200);
    bool rel = false;
    u32 old = __hip_atomic_fetch_add(sub, 1u, __ATOMIC_ACQ_REL, __HIP_MEMORY_SCOPE_AGENT);
    if (old == 31u){
      __hip_atomic_store(sub, 0u, __ATOMIC_RELAXED, __HIP_MEMORY_SCOPE_AGENT);
      u32 mo = __hip_atomic_fetch_add(mcnt, 1u, __ATOMIC_ACQ_REL, __HIP_MEMORY_SCOPE_AGENT);
      if (mo == 7u){
        __hip_atomic_store(mcnt, 0u, __ATOMIC_RELAXED, __HIP_MEMORY_SCOPE_AGENT);
        __hip_atomic_fetch_add(gen, 1u, __ATOMIC_RELEASE, __HIP_MEMORY_SCOPE_AGENT);
        rel = true;
      }
    }
    if (!rel){
      while (__hip_atomic_load(gen, __ATOMIC_ACQUIRE, __HIP_MEMORY_SCOPE_AGENT) < target){
        __builtin_amdgcn_s_sleep(2);
      }
    }
  }
  __syncthreads();
}

__device__ inline u64 shfl_down_u64(u64 x, int d){
  int lo = __shfl_down((int)(u32)(x & 0xFFFFFFFFull), d, 64);
  int hi = __shfl_down((int)(u32)(x >> 32), d, 64);
  return (((u64)(u32)hi)<<32) | (u64)(u32)lo;
}

// ================= init: embed (f32) into out-scratch, zero states/partials =================
__global__ __launch_bounds__(256) void k_init(const int* __restrict__ inp,
    const float* __restrict__ iemb, char* __restrict__ outc, char* __restrict__ ws)
{
  float4* XS4 = (float4*)(outc + OUT_XS);
  const float4* IE4 = (const float4*)iemb;
  float4* HS4 = (float4*)(ws + OFF_HS);
  u64* PART = (u64*)(ws + OFF_PART);
  const int N1 = 262144;          // XS float4: [128][32][64]
  const int N2 = HS_N/4;          // 49152
  const int N3 = 32768;           // PART u64
  const int TOT = N1+N2+N3;
  for (int i = blockIdx.x*256 + threadIdx.x; i < TOT; i += gridDim.x*256){
    int r = i;
    if (r < N1){
      int e4 = r & 63, sb = r >> 6;
      int b2 = sb & 31, s2 = sb >> 5;
      XS4[r] = IE4[(size_t)inp[b2*Sz + s2]*64 + e4];
    } else if ((r -= N1) < N2){
      HS4[r] = make_float4(0.f,0.f,0.f,0.f);
    } else {
      PART[r - N2] = 0ull;
    }
  }
}

// ================= encoder layer scan (both directions concurrently) =================
// grid 256: blocks [0,128) fwd chain, [128,256) bwd.
// NEW decode: q = c&3, b = c>>2  -> blocks sharing a (chain,q) weight slice land on
// only 2 XCDs (blk%8 = (4b+q)%8), so each XCD's slice set (~1.5MB) is L2-resident.
__global__ __launch_bounds__(256) void k_enc(
    const float* __restrict__ Wfi, const float* __restrict__ Wfh, const float* __restrict__ bfv,
    const float* __restrict__ Wbi, const float* __restrict__ Wbh, const float* __restrict__ bbv,
    char* __restrict__ outc, char* __restrict__ ws, int layer)
{
  __shared__ __align__(16) float xh[1024];   // x (<=512) + h (256); glds at +768
  float* glds = xh + 768;
  int tid = threadIdx.x;
  int chain = blockIdx.x >> 7, c = blockIdx.x & 127;
  int q = c & 3, b = c >> 2, j0 = q*64;
  int g = tid >> 6, jj = tid & 63;
  int xK = layer ? 512 : 256;
  const float* X    = (const float*)(outc + (layer ? OUT_XS1 : OUT_XS));
  float*       XS1w = (float*)(outc + OUT_XS1);
  float* HSf = (float*)(ws + OFF_HS);
  float* chbase = HSf + layer*49152 + chain*24576;
  float* cst = chbase + 16384;
  const float* Wih  = chain ? Wbi : Wfi;
  const float* Whh  = chain ? Wbh : Wfh;
  const float* bias = chain ? bbv : bfv;
  int row = g*256 + j0 + jj;
  float bv = bias[row];
  BarSlot* bar = (BarSlot*)ws + (layer ? 64 : 0) + chain*32 + b;
  int dh_off = layer ? HS_H1A : HS_H0A;
  int dc_off = layer ? HS_C1  : HS_C0;
  const float4* wa  = (const float4*)(Wih + (size_t)row*xK);
  const float4* wb2 = (const float4*)(Whh + (size_t)row*256);

  for (int s = 0; s < 128; ++s){
    int xi = chain ? (127 - s) : s;
    const float* hbuf = chbase + (s&1)*8192;
    const float* xrow = X + ((size_t)xi*32 + b)*xK;
    xh[tid] = xrow[tid];
    if (layer) xh[256 + tid] = xrow[256 + tid];
    xh[xK + tid] = hbuf[b*256 + tid];
    __syncthreads();
    float acc = bv;
    int nA4 = xK >> 2;
    #pragma unroll 16
    for (int k4 = 0; k4 < nA4; ++k4){ float4 w = wa[k4]; ACC4(w, xh + (k4<<2)); }
    #pragma unroll 16
    for (int k4 = 0; k4 < 64; ++k4){ float4 w = wb2[k4]; ACC4(w, xh + xK + (k4<<2)); }
    glds[tid] = acc;
    __syncthreads();
    if (tid < 64){
      int j = j0 + tid;
      float iv = sigf(glds[tid]), fv = sigf(glds[64+tid]);
      float gv = tanhf(glds[128+tid]), ov = sigf(glds[192+tid]);
      float cold = cst[b*256 + j];
      float cnew = fv*cold + iv*gv;
      cst[b*256 + j] = cnew;
      float hnew = ov*tanhf(cnew);
      (chbase + ((s+1)&1)*8192)[b*256 + j] = hnew;
      if (layer == 0) XS1w[((size_t)xi*32 + b)*512 + chain*256 + j] = hnew;
      if (s == 127){
        HSf[dh_off + b*512 + chain*256 + j] = hnew;
        HSf[dc_off + b*512 + chain*256 + j] = cnew;
      }
    }
    if (s < 127) block_bar(bar, 4, (u32)(s+1));
  }
}

// ================= decoder: 127 greedy steps, 1024-thread blocks =================
// grid 256 x 1024 (16 waves/block, 1 block/CU -> 4 waves/SIMD).
// Cells on blocks [0,128): jg = blk&15 (j-slice of 32, XCD-pinned since blk%8=jg%8),
//   b4 = blk>>4 (4 batches). Threads: kq = tid>>7 (k-split 8), r = tid&127 (4 gates x 32 j).
//   Each weight float4 feeds 4 batch accumulators (4x traffic amortization).
// Linear on blocks [0,250): 64 vocab rows/block, thread = (vl 0..31 -> 2 v, bb 0..31).
__global__ __launch_bounds__(1024) void k_dec(const float* __restrict__ oemb,
    const float* __restrict__ W0i, const float* __restrict__ W0h, const float* __restrict__ b0v,
    const float* __restrict__ W1i, const float* __restrict__ W1h, const float* __restrict__ b1v,
    const float* __restrict__ linW, const float* __restrict__ linbv, const int* __restrict__ clsp,
    float* __restrict__ out, char* __restrict__ ws)
{
  __shared__ __align__(16) float smem[16384];  // 64KB
  float* xh   = smem;                  // cells: [0,4096) = 4 batches x 1024
  float* glds = smem + 4096;           // cells: [4096,8192) = 4 batches x (8 kq x 128 r)
  int*  stok  = (int*)(smem + 8192);   // 4 resolved tokens
  float* h1s  = smem;                  // linear: full 16384 floats
  u64*  tokred = (u64*)smem;           // linear argmax scratch (1024 u64), after sync

  int tid = threadIdx.x, blk = blockIdx.x;
  int lane = tid & 63, wv = tid >> 6;

  // cell decode
  int jg = blk & 15, b4 = blk >> 4;
  int kq = tid >> 7, r = tid & 127, g = r >> 5, jj = r & 31;
  int rowA = g*512 + jg*32 + jj;

  // linear decode
  int vl = tid >> 5, bb = tid & 31;
  int v0 = blk * 64;
  int v  = v0 + 2*vl;
  int vsafe = (blk < 250) ? v : 0;

  float* HSf = (float*)(ws + OFF_HS);
  u64* PART = (u64*)(ws + OFF_PART);
  BarSlot* bar_b = (BarSlot*)(ws + 1024 + (size_t)(b4 & 7)*128);
  float* c0p = HSf + HS_C0;
  float* c1p = HSf + HS_C1;
  int cls = *clsp;
  u32 tgt_b = 0, tgt_f = 0;
  bool is_cell = (blk < 128);

  // bias preload for combine threads (tid<128): i = tid>>5 (batch), jj2 = tid&31
  float bAi=0,bAf=0,bAg=0,bAo=0,bBi=0,bBf=0,bBg=0,bBo=0;
  if (tid < 128){
    int jc = jg*32 + (tid & 31);
    bAi=b0v[jc]; bAf=b0v[512+jc]; bAg=b0v[1024+jc]; bAo=b0v[1536+jc];
    bBi=b1v[jc]; bBf=b1v[512+jc]; bBg=b1v[1024+jc]; bBo=b1v[1536+jc];
  }
  const float4* wA1 = (const float4*)(W0i + (size_t)rowA*256) + kq*8;    // 8 f4  (xe eighth)
  const float4* wA2 = (const float4*)(W0h + (size_t)rowA*512) + kq*16;   // 16 f4 (h0 eighth)
  const float4* wB1 = (const float4*)(W1i + (size_t)rowA*512) + kq*16;   // 16 f4 (h0 eighth)
  const float4* wB2 = (const float4*)(W1h + (size_t)rowA*512) + kq*16;   // 16 f4 (h1 eighth)
  const float4* wc0 = (const float4*)(linW + (size_t)vsafe*512);
  const float4* wc1 = wc0 + 128;
  float lb0 = linbv[vsafe], lb1 = linbv[vsafe + 1];

  for (int step = 0; step < 127; ++step){
    int p = step & 1;
    float* h0r = HSf + (p ? HS_H0B : HS_H0A);
    float* h0w = HSf + (p ? HS_H0A : HS_H0B);
    float* h1r = HSf + (p ? HS_H1B : HS_H1A);
    float* h1w = HSf + (p ? HS_H1A : HS_H1B);

    if (is_cell){
      // ---- resolve tokens for this block's 4 batches (waves 0..3, one per batch) ----
      if (step == 0){
        if (tid < 4) stok[tid] = cls;
      } else if (wv < 4){
        int bi = b4*4 + wv;
        u64 pk = 0;
        #pragma unroll
        for (int q2 = 0; q2 < 4; ++q2){
          int r2 = q2*64 + lane;
          if (r2 < 250){ u64 e = PART[(size_t)bi*256 + r2]; if (e > pk) pk = e; }
        }
        #pragma unroll
        for (int d = 32; d; d >>= 1){ u64 o = shfl_down_u64(pk, d); if (o > pk) pk = o; }
        if (lane == 0){
          u32 tk = 0xFFFFFFFFu - (u32)(pk & 0xFFFFFFFFull);
          if (tk >= (u32)Vz) tk = 0;
          stok[wv] = (int)tk;
        }
      }
      __syncthreads();

      // ---- dec0 stage: xh[i*1024+o]: o<256 = xe_i, [256,768) = h0_i ----
      {
        int o = tid;
        if (o < 256){
          #pragma unroll
          for (int i = 0; i < 4; ++i) xh[i*1024 + o] = oemb[(size_t)stok[i]*Ez + o];
        } else if (o < 768){
          #pragma unroll
          for (int i = 0; i < 4; ++i) xh[i*1024 + o] = h0r[(size_t)(b4*4+i)*512 + (o-256)];
        }
      }
      __syncthreads();
      // ---- dec0 dot: 24 f4 weight loads feed 4 batches ----
      {
        float acc0=0.f, acc1=0.f, acc2=0.f, acc3=0.f;
        const float* xq = xh + kq*32;
        const float* hq = xh + 256 + kq*64;
        #pragma unroll
        for (int k4 = 0; k4 < 8; ++k4){ float4 w = wA1[k4]; const float* p2 = xq + (k4<<2); ACC4X(w, p2); }
        #pragma unroll 8
        for (int k4 = 0; k4 < 16; ++k4){ float4 w = wA2[k4]; const float* p2 = hq + (k4<<2); ACC4X(w, p2); }
        glds[tid] = acc0; glds[1024+tid] = acc1; glds[2048+tid] = acc2; glds[3072+tid] = acc3;
      }
      __syncthreads();
      if (tid < 128){
        int i = tid >> 5, jj2 = tid & 31;
        int bi = b4*4 + i, j = jg*32 + jj2;
        const float* gb = glds + i*1024;
        float s0=0.f,s1=0.f,s2=0.f,s3=0.f;
        #pragma unroll
        for (int k2 = 0; k2 < 8; ++k2){
          const float* gk = gb + k2*128;
          s0 += gk[jj2]; s1 += gk[32+jj2]; s2 += gk[64+jj2]; s3 += gk[96+jj2];
        }
        float iv = sigf(s0 + bAi), fv = sigf(s1 + bAf);
        float gv = tanhf(s2 + bAg), ov = sigf(s3 + bAo);
        float cold = c0p[(size_t)bi*512 + j];
        float cnew = fv*cold + iv*gv;
        c0p[(size_t)bi*512 + j] = cnew;
        h0w[(size_t)bi*512 + j] = ov*tanhf(cnew);
      }
      block_bar(bar_b, 16, ++tgt_b);

      // ---- dec1 stage: xh[i*1024+o]: o<512 = h0_i, o>=512 = h1_i ----
      {
        int o = tid;
        if (o < 512){
          #pragma unroll
          for (int i = 0; i < 4; ++i) xh[i*1024 + o] = h0w[(size_t)(b4*4+i)*512 + o];
        } else {
          #pragma unroll
          for (int i = 0; i < 4; ++i) xh[i*1024 + o] = h1r[(size_t)(b4*4+i)*512 + (o-512)];
        }
      }
      __syncthreads();
      {
        float acc0=0.f, acc1=0.f, acc2=0.f, acc3=0.f;
        const float* xq = xh + kq*64;
        const float* hq = xh + 512 + kq*64;
        #pragma unroll 8
        for (int k4 = 0; k4 < 16; ++k4){ float4 w = wB1[k4]; const float* p2 = xq + (k4<<2); ACC4X(w, p2); }
        #pragma unroll 8
        for (int k4 = 0; k4 < 16; ++k4){ float4 w = wB2[k4]; const float* p2 = hq + (k4<<2); ACC4X(w, p2); }
        glds[tid] = acc0; glds[1024+tid] = acc1; glds[2048+tid] = acc2; glds[3072+tid] = acc3;
      }
      __syncthreads();
      if (tid < 128){
        int i = tid >> 5, jj2 = tid & 31;
        int bi = b4*4 + i, j = jg*32 + jj2;
        const float* gb = glds + i*1024;
        float s0=0.f,s1=0.f,s2=0.f,s3=0.f;
        #pragma unroll
        for (int k2 = 0; k2 < 8; ++k2){
          const float* gk = gb + k2*128;
          s0 += gk[jj2]; s1 += gk[32+jj2]; s2 += gk[64+jj2]; s3 += gk[96+jj2];
        }
        float iv = sigf(s0 + bBi), fv = sigf(s1 + bBf);
        float gv = tanhf(s2 + bBg), ov = sigf(s3 + bBo);
        float cold = c1p[(size_t)bi*512 + j];
        float cnew = fv*cold + iv*gv;
        c1p[(size_t)bi*512 + j] = cnew;
        h1w[(size_t)bi*512 + j] = ov*tanhf(cnew);
      }
    }

    // ---- barrier #1: h1w published to all blocks ----
    grid_bar(ws, ++tgt_f);

    // ---- linear: stage h1 (rotated +4*b for <=4-way LDS conflicts), GEMV, argmax partials ----
    for (int i2 = tid; i2 < 16384; i2 += 1024){
      int b2 = i2 >> 9, k2 = i2 & 511;
      h1s[(i2 & ~511) | ((k2 + 4*b2) & 511)] = h1w[i2];
    }
    __syncthreads();
    if (blk < 250){
      float a0 = lb0, a1 = lb1;
      const float* hrow = h1s + (bb << 9);
      #pragma unroll 4
      for (int k4 = 0; k4 < 128; ++k4){
        float4 hx = *(const float4*)(hrow + (((k4<<2) + 4*bb) & 511));
        float4 w0 = wc0[k4], w1 = wc1[k4];
        a0=fmaf(w0.x,hx.x,a0); a0=fmaf(w0.y,hx.y,a0); a0=fmaf(w0.z,hx.z,a0); a0=fmaf(w0.w,hx.w,a0);
        a1=fmaf(w1.x,hx.x,a1); a1=fmaf(w1.y,hx.y,a1); a1=fmaf(w1.z,hx.z,a1); a1=fmaf(w1.w,hx.w,a1);
      }
      float* orow = out + ((size_t)bb*Tz + (size_t)(step+1))*Vz + v;
      *(float2*)orow = make_float2(a0, a1);
      if (step == 0){
        float* zrow = out + (size_t)bb*Tz*Vz + v;   // frame 0 one-hot (scratch now dead)
        *(float2*)zrow = make_float2((v==cls)?1.f:0.f, (v+1==cls)?1.f:0.f);
      }
      u32 k0 = f2ord(a0), k1 = f2ord(a1);
      u32 bk = k0; u32 bvv = (u32)v;
      if (k1 > bk){ bk = k1; bvv = (u32)(v+1); }
      u64 pk = (((u64)bk)<<32) | (u64)(0xFFFFFFFFu - bvv);
      __syncthreads();                 // h1s reads done before tokred overwrites smem
      tokred[tid] = pk;                // tid = vl*32 + bb
      __syncthreads();
      if (tid < 32){
        u64 m = tokred[tid];
        for (int q2 = 1; q2 < 32; ++q2){ u64 o = tokred[q2*32 + tid]; if (o > m) m = o; }
        PART[(size_t)tid*256 + blk] = m;
      }
    }
    // ---- barrier #2: PART published; resolve happens at next step start ----
    if (step < 126) grid_bar(ws, ++tgt_f);
    else ++tgt_f;
  }
}

// ================= launch =================
extern "C" void kernel_launch(void* const* d_in, const int* in_sizes, int n_in,
                              void* d_out, int out_size, void* d_ws, size_t ws_size,
                              hipStream_t stream) {
  const int* inputs = (const int*)d_in[0];
  const int* cls    = (const int*)d_in[1];
  const float* in_emb = (const float*)d_in[2];
  const float* out_emb= (const float*)d_in[3];
  const float* e0f_Wih=(const float*)d_in[4],  *e0f_Whh=(const float*)d_in[5],  *e0f_b=(const float*)d_in[6];
  const float* e0b_Wih=(const float*)d_in[7],  *e0b_Whh=(const float*)d_in[8],  *e0b_b=(const float*)d_in[9];
  const float* e1f_Wih=(const float*)d_in[10], *e1f_Whh=(const float*)d_in[11], *e1f_b=(const float*)d_in[12];
  const float* e1b_Wih=(const float*)d_in[13], *e1b_Whh=(const float*)d_in[14], *e1b_b=(const float*)d_in[15];
  const float* d0_Wih =(const float*)d_in[16], *d0_Whh =(const float*)d_in[17], *d0_b =(const float*)d_in[18];
  const float* d1_Wih =(const float*)d_in[19], *d1_Whh =(const float*)d_in[20], *d1_b =(const float*)d_in[21];
  const float* linW   =(const float*)d_in[22], *linb   =(const float*)d_in[23];
  float* out = (float*)d_out;
  char* outc = (char*)d_out;
  char* ws = (char*)d_ws;

  hipMemsetAsync(ws, 0, 4096, stream);  // barrier slots
  k_init<<<1024, 256, 0, stream>>>(inputs, in_emb, outc, ws);
  k_enc<<<256, 256, 0, stream>>>(e0f_Wih, e0f_Whh, e0f_b, e0b_Wih, e0b_Whh, e0b_b, outc, ws, 0);
  k_enc<<<256, 256, 0, stream>>>(e1f_Wih, e1f_Whh, e1f_b, e1b_Wih, e1b_Whh, e1b_b, outc, ws, 1);
  k_dec<<<256, 1024, 0, stream>>>(out_emb, d0_Wih, d0_Whh, d0_b, d1_Wih, d1_Whh, d1_b,
                                  linW, linb, cls, out, ws);
}